// Round 12
// baseline (351.236 us; speedup 1.0000x reference)
//
#include <hip/hip_runtime.h>
#include <math.h>

#define B_    2
#define N_    2048
#define DIM_  1024
#define H_    16
#define HD_   64
#define TDIM  3072      // 3*DIM
#define ROWS  4096      // B*N
#define PI_F  3.14159265358979323846f
#define SCALE_F 0.125f

typedef short short8 __attribute__((ext_vector_type(8)));
typedef float f32x4 __attribute__((ext_vector_type(4)));
typedef float f32x16 __attribute__((ext_vector_type(16)));
typedef unsigned u32x4 __attribute__((ext_vector_type(4)));
typedef unsigned uint2v __attribute__((ext_vector_type(2)));
typedef unsigned short ushort_t;

// 2-op bf16 round (round-half-up)
__device__ __forceinline__ unsigned short f2bf(float x) {
  return (unsigned short)((__float_as_uint(x) + 0x8000u) >> 16);
}
__device__ __forceinline__ float bf2f(unsigned short h) {
  return __uint_as_float(((unsigned)h) << 16);
}
__device__ __forceinline__ float inv_norm(float s) {
  return __builtin_amdgcn_rsqf(fmaxf(s, 1e-24f));
}
// tanh via hw exp2 + rcp (no full-precision divide)
__device__ __forceinline__ float fast_tanh(float x) {
  const float e = __builtin_amdgcn_exp2f(2.885390081777927f * x);  // exp(2x)
  return 1.0f - 2.0f * __builtin_amdgcn_rcpf(e + 1.0f);
}

// DPP lane reductions (VALU, ~4-8cy/level vs ds_bpermute ~30cy)
template <int CTRL>
__device__ __forceinline__ float dpp_addf(float v) {
  int x = __builtin_amdgcn_update_dpp(0, __float_as_int(v), CTRL, 0xF, 0xF, true);
  return v + __int_as_float(x);
}
__device__ __forceinline__ float red16(float s) {   // sum over 16-lane rows
  s = dpp_addf<0xB1>(s);
  s = dpp_addf<0x4E>(s);
  s = dpp_addf<0x141>(s);
  s = dpp_addf<0x140>(s);
  return s;
}
__device__ __forceinline__ float red8(float s) {    // sum over 8-lane groups
  s = dpp_addf<0xB1>(s);
  s = dpp_addf<0x4E>(s);
  s = dpp_addf<0x141>(s);
  return s;
}
// lane i <-> lane i+32 exchange via permlane32_swap (VALU, replaces ds_bpermute)
__device__ __forceinline__ float xchg32(float x, bool hi32) {
  uint2v pr = __builtin_amdgcn_permlane32_swap(__float_as_uint(x),
                                               __float_as_uint(x), false, false);
  return __uint_as_float(hi32 ? pr[0] : pr[1]);
}

// async global->LDS, 16B per lane; LDS dest = wave-uniform base + lane*16
__device__ __forceinline__ void gl_lds16(const void* g, void* l) {
  __builtin_amdgcn_global_load_lds(
      (const __attribute__((address_space(1))) unsigned int*)g,
      (__attribute__((address_space(3))) unsigned int*)l, 16, 0, 0);
}

// ---------------------------------------------------------------------------
// prologue: ALL pre-GEMM prep fused into one launch. Single-block jobs
// (compute_M, prep_w, zero_sumsq) are blocks 0-2 (dispatched first) and hide
// under the 4096-block split_X stream + 768-block split_W.
// ---------------------------------------------------------------------------
__global__ __launch_bounds__(256) void prologue(
    const float* __restrict__ X, const float* __restrict__ Wqkv,
    const float* __restrict__ Wf, const float* __restrict__ Wp1,
    const float* __restrict__ Wp2,
    unsigned short* __restrict__ Xs, unsigned short* __restrict__ Wt,
    ushort_t* __restrict__ Ms, ushort_t* __restrict__ W1s,
    ushort_t* __restrict__ W2s, float* __restrict__ sumsq) {
  __shared__ __align__(16) char pls[32768];
  const int bid = blockIdx.x;
  const int tid = threadIdx.x;

  if (bid == 0) {
    // ---- compute_M: M = (I + 0.1*Wf)^10 via A^2,A^4,A^8,A^10 (4 matmuls).
    float* P = (float*)pls;
    float* Q = (float*)(pls + 16384);
    for (int i = tid; i < 4096; i += 256)
      P[i] = 0.1f * Wf[i] + (((i >> 6) == (i & 63)) ? 1.0f : 0.0f);
    __syncthreads();
    float acc[16];
#define MM64(Xb, Yb) \
    _Pragma("unroll") \
    for (int jo = 0; jo < 16; ++jo) { \
      const int i_ = tid + jo * 256; \
      const int r_ = i_ >> 6, c_ = i_ & 63; \
      float s0 = 0.f, s1 = 0.f, s2 = 0.f, s3 = 0.f; \
      _Pragma("unroll") \
      for (int e = 0; e < 64; e += 4) { \
        s0 = fmaf(Xb[r_ * 64 + e],     Yb[e * 64 + c_], s0); \
        s1 = fmaf(Xb[r_ * 64 + e + 1], Yb[(e + 1) * 64 + c_], s1); \
        s2 = fmaf(Xb[r_ * 64 + e + 2], Yb[(e + 2) * 64 + c_], s2); \
        s3 = fmaf(Xb[r_ * 64 + e + 3], Yb[(e + 3) * 64 + c_], s3); \
      } \
      acc[jo] = (s0 + s1) + (s2 + s3); \
    }
    MM64(P, P)
#pragma unroll
    for (int jo = 0; jo < 16; ++jo) Q[tid + jo * 256] = acc[jo];
    __syncthreads();
    MM64(Q, Q)
#pragma unroll
    for (int jo = 0; jo < 16; ++jo) P[tid + jo * 256] = acc[jo];
    __syncthreads();
    MM64(P, P)
    __syncthreads();
#pragma unroll
    for (int jo = 0; jo < 16; ++jo) P[tid + jo * 256] = acc[jo];
    __syncthreads();
    MM64(P, Q)
#pragma unroll
    for (int jo = 0; jo < 16; ++jo) {
      const int i_ = tid + jo * 256;
      const int r_ = i_ >> 6, c_ = i_ & 63;
      const ushort_t hi = f2bf(acc[jo]);
      Ms[c_ * 64 + r_] = hi;
      Ms[4096 + c_ * 64 + r_] = f2bf(acc[jo] - bf2f(hi));
    }
#undef MM64
  } else if (bid == 1) {
    // ---- prep_w
    for (int i = tid; i < 8192; i += 256) {
      const int n = i >> 6, k = i & 63;
      const float v = Wp1[k * 128 + n];
      const ushort_t hi = f2bf(v);
      W1s[i] = hi; W1s[8192 + i] = f2bf(v - bf2f(hi));
    }
    for (int i = tid; i < 8192; i += 256) {
      const int n = i >> 7, k = i & 127;
      const float v = Wp2[k * 64 + n];
      const ushort_t hi = f2bf(v);
      W2s[i] = hi; W2s[8192 + i] = f2bf(v - bf2f(hi));
    }
  } else if (bid == 2) {
    // ---- zero_sumsq
#pragma unroll
    for (int j = 0; j < 16; ++j) sumsq[j * 256 + tid] = 0.0f;
  } else if (bid < 771) {
    // ---- split_W: 768 blocks
    const int wb = bid - 3;
    const int n0 = (wb % 48) * 64, k0 = (wb / 48) * 64;
    float (*T)[68] = (float(*)[68])pls;
    for (int l = tid; l < 1024; l += 256) {
      const int r = l >> 4, c = (l & 15) * 4;
      *(float4*)&T[r][c] = *(const float4*)&Wqkv[(size_t)(k0 + r) * TDIM + n0 + c];
    }
    __syncthreads();
    const int n = tid >> 2, q = (tid & 3) * 16;
    alignas(16) unsigned short hi16[16];
    alignas(16) unsigned short lo16[16];
#pragma unroll
    for (int j = 0; j < 16; ++j) {
      const float v = T[q + j][n];
      const unsigned short h = f2bf(v);
      hi16[j] = h; lo16[j] = f2bf(v - bf2f(h));
    }
    unsigned short* dst = &Wt[(size_t)(n0 + n) * 2048];
    *(uint4*)&dst[k0 + q]            = *(uint4*)&hi16[0];
    *(uint4*)&dst[k0 + q + 8]        = *(uint4*)&hi16[8];
    *(uint4*)&dst[1024 + k0 + q]     = *(uint4*)&lo16[0];
    *(uint4*)&dst[1024 + k0 + q + 8] = *(uint4*)&lo16[8];
  } else {
    // ---- split_X: 4096 blocks
    const int gid = (bid - 771) * 256 + tid;
    const int m = gid >> 8, c = (gid & 255) * 4;
    float4 v = *(const float4*)&X[(size_t)m * 1024 + c];
    ushort4 hi, lo;
    hi.x = f2bf(v.x); lo.x = f2bf(v.x - bf2f(hi.x));
    hi.y = f2bf(v.y); lo.y = f2bf(v.y - bf2f(hi.y));
    hi.z = f2bf(v.z); lo.z = f2bf(v.z - bf2f(hi.z));
    hi.w = f2bf(v.w); lo.w = f2bf(v.w - bf2f(hi.w));
    *(ushort4*)&Xs[(size_t)m * 2048 + c] = hi;
    *(ushort4*)&Xs[(size_t)m * 2048 + 1024 + c] = lo;
  }
}

// ---------------------------------------------------------------------------
// gemm10: 256x192 tile, grid 256 blocks = 1/CU, 8 waves as 4M x 2N.
// Barrier-minimized schedule (R11, verified): 5 barriers/k, counted vmcnt.
// ---------------------------------------------------------------------------
#define BAR   __builtin_amdgcn_s_barrier()
#define LGKM  asm volatile("s_waitcnt lgkmcnt(0)")
#define SB    __builtin_amdgcn_sched_barrier(0)
#define PRIO1 __builtin_amdgcn_s_setprio(1)
#define PRIO0 __builtin_amdgcn_s_setprio(0)
#define WAITV(n) asm volatile("s_waitcnt vmcnt(" #n ")")

__global__ __launch_bounds__(512, 2) void gemm10(const unsigned short* __restrict__ Xs,
                                                 const unsigned short* __restrict__ Wt,
                                                 const float* __restrict__ bias,
                                                 float* __restrict__ C,
                                                 float* __restrict__ sumsq) {
  __shared__ __align__(16) ushort_t Ab[2][256 * 64];   // 2 x 32 KiB
  __shared__ __align__(16) ushort_t Bb0[192 * 64];     // 24 KiB (hi)
  __shared__ __align__(16) ushort_t Bb1[192 * 64];     // 24 KiB (lo)
  const int tid = threadIdx.x;
  const int wv = tid >> 6, ln = tid & 63;
  const int l16 = ln & 15, quad = ln >> 4;
  const int wm = wv >> 1, wn = wv & 1;         // 4M x 2N waves
  // XCD-aware bijective swizzle (256 % 8 == 0)
  const int flat = blockIdx.x;
  const int swz = (flat & 7) * 32 + (flat >> 3);
  const int row0 = (swz >> 4) * 256, col0 = (swz & 15) * 192;
  const int lr = ln >> 3, sg8 = (ln & 7) ^ lr;   // staging sub-row + swizzled slot

  f32x4 acc[4][6];
#pragma unroll
  for (int i = 0; i < 4; ++i)
#pragma unroll
    for (int j = 0; j < 6; ++j) acc[i][j] = {0.f, 0.f, 0.f, 0.f};

#define STAGE_A(dstBuf, koff) do { \
    _Pragma("unroll") for (int j_ = 0; j_ < 4; ++j_) { \
      const int g_ = wv + j_ * 8; \
      gl_lds16(&Xs[(size_t)(row0 + g_ * 8 + lr) * 2048 + (koff) + sg8 * 8], \
               (char*)(dstBuf) + g_ * 1024); \
    } \
  } while (0)
#define STAGE_B(dstBuf, koff) do { \
    _Pragma("unroll") for (int j_ = 0; j_ < 3; ++j_) { \
      const int g_ = wv + j_ * 8; \
      gl_lds16(&Wt[(size_t)(col0 + g_ * 8 + lr) * 2048 + (koff) + sg8 * 8], \
               (char*)(dstBuf) + g_ * 1024); \
    } \
  } while (0)

#define LDA(Abuf, mh) do { \
    _Pragma("unroll") for (int j_ = 0; j_ < 2; ++j_) { \
      const int rr_ = wm * 64 + (mh) * 32 + j_ * 16 + l16; \
      _Pragma("unroll") for (int kk_ = 0; kk_ < 2; ++kk_) \
        afr[j_][kk_] = *(const short8*)&(Abuf)[rr_ * 64 + (((kk_ * 4 + quad) ^ (l16 & 7)) * 8)]; \
    } \
  } while (0)

#define LDB(Bbuf, nh) do { \
    _Pragma("unroll") for (int j_ = 0; j_ < 3; ++j_) { \
      const int rr_ = wn * 96 + (nh) * 48 + j_ * 16 + l16; \
      _Pragma("unroll") for (int kk_ = 0; kk_ < 2; ++kk_) \
        bfr[(nh) * 3 + j_][kk_] = *(const short8*)&(Bbuf)[rr_ * 64 + (((kk_ * 4 + quad) ^ (l16 & 7)) * 8)]; \
    } \
  } while (0)

#define MFMA_Q(mh, nh) do { \
    _Pragma("unroll") for (int j_ = 0; j_ < 2; ++j_) \
    _Pragma("unroll") for (int i_ = 0; i_ < 3; ++i_) \
    _Pragma("unroll") for (int kk_ = 0; kk_ < 2; ++kk_) \
      acc[(mh) * 2 + j_][(nh) * 3 + i_] = __builtin_amdgcn_mfma_f32_16x16x32_bf16( \
          afr[j_][kk_], bfr[(nh) * 3 + i_][kk_], acc[(mh) * 2 + j_][(nh) * 3 + i_], 0, 0, 0); \
  } while (0)

  // prologue: issue order Bhi0, Ahi0, Alo0, Blo0; keep newest 7 in flight
  STAGE_B(Bb0, 0);
  STAGE_A(Ab[0], 0);
  STAGE_A(Ab[1], 1024);
  STAGE_B(Bb1, 1024);
  WAITV(7);
  BAR;

  short8 afr[2][2], bfr[6][2];
#pragma unroll 2
  for (int k = 0; k < 16; ++k) {
    ushort_t* Ahi = Ab[k & 1];
    ushort_t* Alo = Ab[(k & 1) ^ 1];
    const int kn = (k + 1) * 64;
    const bool more = (k < 15);

    // ======== tile 0: Ahi x Bhi (no staging, no intra-tile barriers) ====
    LDA(Ahi, 0); LDB(Bb0, 0);
    PRIO1; MFMA_Q(0, 0); PRIO0;
    LDB(Bb0, 1);
    PRIO1; MFMA_Q(0, 1); PRIO0;
    LDA(Ahi, 1);
    PRIO1; MFMA_Q(1, 0); PRIO0;
    PRIO1; MFMA_Q(1, 1); PRIO0;
    WAITV(3); SB; BAR;             // Alo_k landed & visible (keep Blo_k)

    // ======== tile 1: Alo x Bhi ========
    LDA(Alo, 0); LDB(Bb0, 0);
    PRIO1; MFMA_Q(0, 0); PRIO0;
    LDB(Bb0, 1);
    PRIO1; MFMA_Q(0, 1); PRIO0;
    LGKM; SB; BAR;                 // all waves' Bb0 reads complete
    if (more) STAGE_B(Bb0, kn);    // Bhi_{k+1}
    LDA(Alo, 1);
    PRIO1; MFMA_Q(1, 0); PRIO0;
    PRIO1; MFMA_Q(1, 1); PRIO0;
    LGKM;                          // all own Alo reads complete
    if (more) { WAITV(3); }        // drain Blo_k (t2 reads it), keep Bhi'
    else      { WAITV(0); }
    SB; BAR;
    if (more) STAGE_A(Alo, kn);    // Ahi_{k+1} -> A[(k+1)&1]

    // ======== tile 2: Ahi x Blo ========
    LDA(Ahi, 0); LDB(Bb1, 0);
    PRIO1; MFMA_Q(0, 0); PRIO0;
    LDB(Bb1, 1);
    PRIO1; MFMA_Q(0, 1); PRIO0;
    LDA(Ahi, 1);
    PRIO1; MFMA_Q(1, 0); PRIO0;
    PRIO1; MFMA_Q(1, 1); PRIO0;
    LGKM; SB; BAR;                 // all waves' Ahi/Bb1 reads complete
    if (more) { STAGE_A(Ahi, 1024 + kn); STAGE_B(Bb1, 1024 + kn); } // Alo',Blo'
    if (more) { WAITV(7); }        // drain Bhi'+Ahi', keep Alo'+Blo'
    else      { WAITV(0); }
    SB; BAR;                       // next-k inputs visible
  }
#undef STAGE_A
#undef STAGE_B
#undef LDA
#undef LDB
#undef MFMA_Q

  // ---- epilogue: bias + store + per-row sumsq (DPP 16-lane reduce)
  float ps[4][4];
#pragma unroll
  for (int mi = 0; mi < 4; ++mi)
#pragma unroll
    for (int r = 0; r < 4; ++r) ps[mi][r] = 0.f;
#pragma unroll
  for (int ni = 0; ni < 6; ++ni) {
    const int col = col0 + wn * 96 + ni * 16 + l16;
    const float bb = bias[col];
#pragma unroll
    for (int mi = 0; mi < 4; ++mi) {
#pragma unroll
      for (int r = 0; r < 4; ++r) {
        const int row = row0 + wm * 64 + mi * 16 + quad * 4 + r;
        const float o = acc[mi][ni][r] + bb;
        C[(size_t)row * TDIM + col] = o;
        ps[mi][r] = fmaf(o, o, ps[mi][r]);
      }
    }
  }
#pragma unroll
  for (int mi = 0; mi < 4; ++mi) {
#pragma unroll
    for (int r = 0; r < 4; ++r) {
      const float v = red16(ps[mi][r]);
      if (l16 == 0)
        atomicAdd(&sumsq[row0 + wm * 64 + mi * 16 + quad * 4 + r], v);
    }
  }
}

// ---------------------------------------------------------------------------
// prep_wave: barrier-free per-wave prep. (256,6): current lean code allocates
// 56 VGPR naturally (cap at min-waves=6 is 85, so no squeeze expected unlike
// R6's (256,8) which collapsed to 32); residency empirically tracks the
// declared min-waves (R6: 79% occ at 8, R7/R10: 38% at 4) -> expect ~6
// blocks/CU and more chain overlap. If VGPR collapses, verdict is final.
// ---------------------------------------------------------------------------
__global__ __launch_bounds__(256, 6) void prep_wave(
    const float* __restrict__ qkv, const float* __restrict__ sumsq,
    const ushort_t* __restrict__ W1s, const float* __restrict__ bp1,
    const ushort_t* __restrict__ W2s, const float* __restrict__ bp2,
    const ushort_t* __restrict__ Ms,
    ushort_t* __restrict__ Qc, ushort_t* __restrict__ Kc,
    ushort_t* __restrict__ Vt) {
  __shared__ __align__(16) char smem[4 * 4608];
  const int tid = threadIdx.x;
  const int wv = tid >> 6, ln = tid & 63;
  const int l16 = ln & 15, quad = ln >> 4;
  const bool hi32 = (ln >= 32);
  char* wscr = smem + wv * 4608;
  ushort_t (*T)[72]   = (ushort_t(*)[72])(wscr);           // 2304 B
  ushort_t (*Z0)[72]  = (ushort_t(*)[72])(wscr);           // alias T (post-amp)
  ushort_t (*Hs)[72]  = (ushort_t(*)[72])(wscr + 2304);    // 2304 B (half-H)
  ushort_t (*Vs)[72]  = (ushort_t(*)[72])(wscr + 2304);    // alias Hs (pre-L1)
  ushort_t (*Z1)[72]  = (ushort_t(*)[72])(wscr + 2304);    // alias Hs (post-aH)

  const int gw = blockIdx.x * 4 + wv;
  const int p0 = gw * 8;
  const int bh = p0 >> 11, n0 = p0 & 2047;
  const int b = bh >> 4, h = bh & 15;

  // ---- stage A: T A-frags (regs) + T scratch + row norms + V out
  short8 aTh[2], aTl[2];
  float invt_l;   // inv row norm for MLP row l16 (held by all quads)
  {
    const int tp = l16 & 7, tisk = l16 >> 3;
    const size_t tb = ((size_t)(b * N_ + n0 + tp)) * TDIM + h * HD_ +
                      tisk * 1024 + quad * 8;
    const float inv = inv_norm(sumsq[b * N_ + n0 + tp]);
    float tvv[16];
    float4 t0 = *(const float4*)&qkv[tb];
    float4 t1 = *(const float4*)&qkv[tb + 4];
    float4 t2 = *(const float4*)&qkv[tb + 32];
    float4 t3 = *(const float4*)&qkv[tb + 36];
    tvv[0]=t0.x*inv; tvv[1]=t0.y*inv; tvv[2]=t0.z*inv; tvv[3]=t0.w*inv;
    tvv[4]=t1.x*inv; tvv[5]=t1.y*inv; tvv[6]=t1.z*inv; tvv[7]=t1.w*inv;
    tvv[8]=t2.x*inv; tvv[9]=t2.y*inv; tvv[10]=t2.z*inv; tvv[11]=t2.w*inv;
    tvv[12]=t3.x*inv; tvv[13]=t3.y*inv; tvv[14]=t3.z*inv; tvv[15]=t3.w*inv;
    float s = 0.f;
#pragma unroll
    for (int j = 0; j < 16; ++j) s = fmaf(tvv[j], tvv[j], s);
    s += __shfl_xor(s, 16, 64);
    s += xchg32(s, hi32);
    invt_l = inv_norm(s);
    alignas(16) ushort_t hh[16];
    alignas(16) ushort_t llo[16];
#pragma unroll
    for (int j = 0; j < 16; ++j) {
      hh[j] = f2bf(tvv[j]);
      llo[j] = f2bf(tvv[j] - bf2f(hh[j]));
    }
    aTh[0] = *(const short8*)&hh[0]; aTh[1] = *(const short8*)&hh[8];
    aTl[0] = *(const short8*)&llo[0]; aTl[1] = *(const short8*)&llo[8];
    *(uint4*)&T[l16][quad * 8]      = *(const uint4*)&hh[0];
    *(uint4*)&T[l16][32 + quad * 8] = *(const uint4*)&hh[8];
  }
  // ---- V: |t|/||t||, transpose via scratch, one 16B store per lane
  {
    const int vp = ln >> 3, vc = (ln & 7) * 8;
    const size_t vb = ((size_t)(b * N_ + n0 + vp)) * TDIM + h * HD_ + 2048 + vc;
    float vv[8];
    float4 v0 = *(const float4*)&qkv[vb];
    float4 v1 = *(const float4*)&qkv[vb + 4];
    vv[0]=v0.x; vv[1]=v0.y; vv[2]=v0.z; vv[3]=v0.w;
    vv[4]=v1.x; vv[5]=v1.y; vv[6]=v1.z; vv[7]=v1.w;
    float sv = 0.f;
#pragma unroll
    for (int j = 0; j < 8; ++j) sv = fmaf(vv[j], vv[j], sv);
    sv = red8(sv);
    const float vinv = inv_norm(sv);
    alignas(16) ushort_t vb16[8];
#pragma unroll
    for (int j = 0; j < 8; ++j) vb16[j] = f2bf(fabsf(vv[j]) * vinv);
    *(uint4*)&Vs[vp][vc] = *(const uint4*)&vb16[0];
    alignas(16) ushort_t ov[8];
#pragma unroll
    for (int p = 0; p < 8; ++p) ov[p] = Vs[p][ln];
    *(uint4*)&Vt[((size_t)(bh * 64) + ln) * N_ + n0] = *(const uint4*)&ov[0];
  }
  // invt by output row (quad*4+r)
  float invt_r[4];
#pragma unroll
  for (int r = 0; r < 4; ++r) invt_r[r] = __shfl(invt_l, quad * 4 + r, 64);

  // ---- L1: H = tanh(T @ Wp1 + b1) [16 x 128], in two column-halves through
  //      the half-size Hs buffer (aH regs read between halves).  (48 MFMA)
  short8 aH[4];
#pragma unroll
  for (int half = 0; half < 2; ++half) {
#pragma unroll
    for (int ct = 0; ct < 4; ++ct) {
      const int colg = half * 64 + ct * 16 + l16;
      f32x4 c = {0.f, 0.f, 0.f, 0.f};
#pragma unroll
      for (int s = 0; s < 2; ++s) {
        short8 wh = *(const short8*)&W1s[(size_t)colg * 64 + s * 32 + quad * 8];
        short8 wl = *(const short8*)&W1s[8192 + (size_t)colg * 64 + s * 32 + quad * 8];
        c = __builtin_amdgcn_mfma_f32_16x16x32_bf16(aTh[s], wh, c, 0, 0, 0);
        c = __builtin_amdgcn_mfma_f32_16x16x32_bf16(aTh[s], wl, c, 0, 0, 0);
        c = __builtin_amdgcn_mfma_f32_16x16x32_bf16(aTl[s], wh, c, 0, 0, 0);
      }
      const float bb = bp1[colg];
#pragma unroll
      for (int r = 0; r < 4; ++r)
        Hs[quad * 4 + r][ct * 16 + l16] = f2bf(fast_tanh(c[r] + bb));
    }
    aH[half * 2]     = *(const short8*)&Hs[l16][quad * 8];
    aH[half * 2 + 1] = *(const short8*)&Hs[l16][32 + quad * 8];
  }

  // ---- L2 + z: rev = tanh(H@Wp2 + b2)*0.5 (revolutions: pi folds away);
  //      z = amp * e^{i*2*pi*rev} via hw v_sin/v_cos  (32 MFMA)
  {
#pragma unroll
    for (int ct = 0; ct < 4; ++ct) {
      const int d = ct * 16 + l16;
      f32x4 c = {0.f, 0.f, 0.f, 0.f};
#pragma unroll
      for (int s = 0; s < 4; ++s) {
        short8 wh = *(const short8*)&W2s[(size_t)d * 128 + s * 32 + quad * 8];
        short8 wl = *(const short8*)&W2s[8192 + (size_t)d * 128 + s * 32 + quad * 8];
        c = __builtin_amdgcn_mfma_f32_16x16x32_bf16(aH[s], wh, c, 0, 0, 0);
        c = __builtin_amdgcn_mfma_f32_16x16x32_bf16(aH[s], wl, c, 0, 0, 0);
      }
      const float b2v = bp2[d];
#pragma unroll
      for (int r = 0; r < 4; ++r) {
        const int row = quad * 4 + r;
        const float rev = fast_tanh(c[r] + b2v) * 0.5f;   // in [-0.5, 0.5]
        const float amp = bf2f(T[row][d]) * invt_r[r];
        const float sp = __builtin_amdgcn_sinf(rev);
        const float cp = __builtin_amdgcn_cosf(rev);
        Z0[row][d] = f2bf(amp * cp);   // overwrites T cell just read (in-order)
        Z1[row][d] = f2bf(amp * sp);   // overwrites dead Hs region
      }
    }
  }

  // ---- flow: F = Z @ M, kept in C-layout registers  (32 MFMA)
  f32x4 cc[2][4];
  {
    short8 aZ[2][2];
#pragma unroll
    for (int s = 0; s < 2; ++s) {
      aZ[0][s] = *(const short8*)&Z0[l16][s * 32 + quad * 8];
      aZ[1][s] = *(const short8*)&Z1[l16][s * 32 + quad * 8];
    }
#pragma unroll
    for (int ct = 0; ct < 4; ++ct) {
      const int colg = ct * 16 + l16;
      short8 mh[2], ml[2];
#pragma unroll
      for (int s = 0; s < 2; ++s) {
        mh[s] = *(const short8*)&Ms[(size_t)colg * 64 + s * 32 + quad * 8];
        ml[s] = *(const short8*)&Ms[4096 + (size_t)colg * 64 + s * 32 + quad * 8];
      }
#pragma unroll
      for (int comp = 0; comp < 2; ++comp) {
        f32x4 c = {0.f, 0.f, 0.f, 0.f};
#pragma unroll
        for (int s = 0; s < 2; ++s) {
          c = __builtin_amdgcn_mfma_f32_16x16x32_bf16(aZ[comp][s], mh[s], c, 0, 0, 0);
          c = __builtin_amdgcn_mfma_f32_16x16x32_bf16(aZ[comp][s], ml[s], c, 0, 0, 0);
        }
        cc[comp][ct] = c;
      }
    }
  }

  // ---- normalize + transport, natively in C-layout.
  const bool isk = quad >= 2;
#pragma unroll
  for (int r = 0; r < 4; ++r) {
    float fr[4], fi[4];
#pragma unroll
    for (int ct = 0; ct < 4; ++ct) { fr[ct] = cc[0][ct][r]; fi[ct] = cc[1][ct][r]; }
    float s = 0.f;
#pragma unroll
    for (int ct = 0; ct < 4; ++ct) s += fmaf(fr[ct], fr[ct], fi[ct] * fi[ct]);
    s = red16(s);
    const float invn_ = inv_norm(s);
#pragma unroll
    for (int ct = 0; ct < 4; ++ct) { fr[ct] *= invn_; fi[ct] *= invn_; }
    float or_[4], oi_[4];
#pragma unroll
    for (int ct = 0; ct < 4; ++ct) {
      or_[ct] = xchg32(fr[ct], hi32);
      oi_[ct] = xchg32(fi[ct], hi32);
    }
    float qr[4], qi[4], kr[4], ki[4];
#pragma unroll
    for (int ct = 0; ct < 4; ++ct) {
      qr[ct] = isk ? or_[ct] : fr[ct];
      qi[ct] = isk ? oi_[ct] : fi[ct];
      kr[ct] = isk ? fr[ct] : or_[ct];
      ki[ct] = isk ? fi[ct] : oi_[ct];
    }
    float sA = 0.f, sB = 0.f;
    float dr[4], di[4];
#pragma unroll
    for (int ct = 0; ct < 4; ++ct) {
      dr[ct] = kr[ct] - qr[ct];
      di[ct] = ki[ct] - qi[ct];
      sA += fmaf(dr[ct], dr[ct], -di[ct] * di[ct]);
      sB += 2.0f * dr[ct] * di[ct];
    }
    sA = red16(sA);
    sB = red16(sB);
    const float rad = __builtin_amdgcn_sqrtf(fmaf(sA, sA, sB * sB));
    const float ur = __builtin_amdgcn_sqrtf(fmaxf((rad + sA) * 0.5f, 0.0f));
    const float ui = copysignf(__builtin_amdgcn_sqrtf(fmaxf((rad - sA) * 0.5f, 0.0f)), sB);
    // exp(10*ur) = 2^(10*log2e*ur); sincos(10*ui) via hw (revolutions)
    const float er = __builtin_amdgcn_exp2f(14.426950408889634f * ur);
    const float rv = 1.5915494309189535f * ui;   // 10*ui / (2*pi)
    const float s10 = __builtin_amdgcn_sinf(rv);
    const float c10 = __builtin_amdgcn_cosf(rv);
    const float exr = er * c10, exi = er * s10;
    const float dnr = 1.0f + exr, dni = exi;
    const float rd2 = __builtin_amdgcn_rcpf(fmaf(dnr, dnr, dni * dni));
    const float tfr = dnr * rd2, tfi = -dni * rd2;
    const float omr = 1.0f - tfr, omi = -tfi;
    float ktr[4], kti[4];
    float s2 = 0.f;
#pragma unroll
    for (int ct = 0; ct < 4; ++ct) {
      ktr[ct] = kr[ct] * tfr - ki[ct] * tfi + qr[ct] * omr - qi[ct] * omi;
      kti[ct] = kr[ct] * tfi + ki[ct] * tfr + qr[ct] * omi + qi[ct] * omr;
      s2 += fmaf(ktr[ct], ktr[ct], kti[ct] * kti[ct]);
    }
    s2 = red16(s2);
    const float inv2 = inv_norm(s2);
    const int p = (quad & 1) * 4 + r;
    const size_t o = ((size_t)bh * N_ + n0 + p) * 128;
    if (!isk) {
#pragma unroll
      for (int ct = 0; ct < 4; ++ct) {
        const int d = ct * 16 + l16;
        Qc[o + d]      = f2bf(qr[ct]);
        Qc[o + 64 + d] = f2bf(qi[ct]);
      }
    } else {
#pragma unroll
      for (int ct = 0; ct < 4; ++ct) {
        const int d = ct * 16 + l16;
        Kc[o + d]      = f2bf(ktr[ct] * inv2);
        Kc[o + 64 + d] = f2bf(-kti[ct] * inv2);   // negated: S = qr.kr + qi.(-ki)
      }
    }
  }
}

// ---------------------------------------------------------------------------
// attn3: 32x32x16 MFMA flash. K prefetch via gl_lds16 double-buffer (R10).
// NEW: V prefetched 1 tile ahead into just 2 uint4 regs (R8's spill came
// from 6 regs; 2 is light). Issue order K(t+1) then V(t+1): next iter's
// ds_write of the V regs makes the compiler wait vmcnt covering BOTH (V
// loads are youngest) -> same safety invariant, but the drain lands after
// a full compute phase of hiding instead of mid-phase.
// ---------------------------------------------------------------------------
__global__ __launch_bounds__(256, 2) void attn3(
    const ushort_t* __restrict__ Qc, const ushort_t* __restrict__ Kc,
    const ushort_t* __restrict__ Vt, float* __restrict__ out) {
  __shared__ __align__(16) char smem[49664];
  ushort_t* Vs = (ushort_t*)(smem + 32768);   // 16 KiB
  float (*Of)[68] = (float(*)[68])smem;       // 34816 B, aliases K bufs
  float* Dd = (float*)(smem + 49152);

  const int tid = threadIdx.x;
  const int wv = tid >> 6, ln = tid & 63;
  const int l31 = ln & 31, hi = ln >> 5;
  const int l16 = ln & 15, quad = ln >> 4;
  const int qh = wv & 1, kh = wv >> 1;
  const int bh = blockIdx.y;
  const int q0 = blockIdx.x * 128;
  const size_t hb = (size_t)bh * N_;

  // K stage via gl_lds16: linear LDS slot u = i*256 + wv*64 + ln maps to
  // row r = u>>4, slot = u&15; source col c = slot ^ (r&15)  (pre-swizzled).
#define STAGE_K(dst, kt) do { \
    const size_t kb_ = (hb + (size_t)(kt) * 64) * 128; \
    _Pragma("unroll") for (int i_ = 0; i_ < 4; ++i_) { \
      const int r_ = i_ * 16 + wv * 4 + quad; \
      const int c_ = l16 ^ (r_ & 15); \
      gl_lds16(&Kc[kb_ + (size_t)r_ * 128 + c_ * 8], \
               (char*)(dst) + (i_ * 256 + wv * 64) * 16); \
    } \
  } while (0)

  short8 qf[2][8];
#pragma unroll
  for (int nt = 0; nt < 2; ++nt) {
    const size_t qrow = (hb + q0 + qh * 64 + nt * 32 + l31) * 128;
#pragma unroll
    for (int s = 0; s < 8; ++s)
      qf[nt][s] = *(const short8*)&Qc[qrow + s * 16 + hi * 8];
  }

  f32x16 oacc[2][2];
#pragma unroll
  for (int i = 0; i < 2; ++i)
#pragma unroll
    for (int j = 0; j < 2; ++j)
#pragma unroll
      for (int r = 0; r < 16; ++r) oacc[i][j][r] = 0.f;
  float den[2] = {0.f, 0.f};

  // V staging lane->element maps (constant across iterations)
  const int vrA = (tid + 0)   >> 3, vcA = (tid + 0)   & 7;
  const int vrB = (tid + 256) >> 3, vcB = (tid + 256) & 7;

  STAGE_K((ushort_t*)smem, 0);   // K tile 0 in flight
  uint4 vreg0, vreg1;            // V tile 0 prefetch (2 regs only)
  vreg0 = *(const uint4*)&Vt[((size_t)bh * 64 + vrA) * N_ + vcA * 8];
  vreg1 = *(const uint4*)&Vt[((size_t)bh * 64 + vrB) * N_ + vcB * 8];

  const int rK = kh * 32 + l31;
  for (int kt = 0; kt < N_ / 64; ++kt) {
    ushort_t* Ks = (ushort_t*)(smem + (kt & 1) * 16384);
    ushort_t* Kn = (ushort_t*)(smem + ((kt & 1) ^ 1) * 16384);
    BAR;   // all waves done reading Vs + Kn(=prev Ks) from previous iter

    // ds_write of vregs: compiler waits on the V loads (youngest) -> drains
    // ALL older vmem incl. this tile's K loads. Same invariant as R10, but
    // the wait lands after a full compute phase of hiding.
    *(uint4*)&Vs[vrA * 128 + ((vcA ^ (vrA & 15)) * 8)] = vreg0;
    *(uint4*)&Vs[vrB * 128 + ((vcB ^ (vrB & 15)) * 8)] = vreg1;
    if (kt + 1 < N_ / 64) {
      STAGE_K(Kn, kt + 1);           // issue K(t+1) first...
      vreg0 = *(const uint4*)&Vt[((size_t)bh * 64 + vrA) * N_ + (kt + 1) * 64 + vcA * 8];
      vreg1 = *(const uint4*)&Vt[((size_t)bh * 64 + vrB) * N_ + (kt + 1) * 64 + vcB * 8];
    }                                // ...then V(t+1) (youngest)
    LGKM; SB;
    BAR;   // Vs visible; K(t+1)/V(t+1) stay in flight across this barrier

    f32x16 sacc[2];
#pragma unroll
    for (int nt = 0; nt < 2; ++nt)
#pragma unroll
      for (int r = 0; r < 16; ++r) sacc[nt][r] = 0.f;
#pragma unroll
    for (int s = 0; s < 8; ++s) {
      const int c = s * 2 + hi;
      short8 ak = *(const short8*)&Ks[rK * 128 + ((c ^ (rK & 15)) * 8)];
      sacc[0] = __builtin_amdgcn_mfma_f32_32x32x16_bf16(ak, qf[0][s], sacc[0], 0, 0, 0);
      sacc[1] = __builtin_amdgcn_mfma_f32_32x32x16_bf16(ak, qf[1][s], sacc[1], 0, 0, 0);
    }

    short8 pfrag[2][2];
#pragma unroll
    for (int nt = 0; nt < 2; ++nt) {
      float pv[16];
      float dl = 0.f;
#pragma unroll
      for (int r = 0; r < 16; ++r) {
        pv[r] = __expf(sacc[nt][r] * SCALE_F);
        dl += pv[r];
      }
      den[nt] += dl;
      unsigned u8a[8], pu[8];
#pragma unroll
      for (int t = 0; t < 8; ++t)
        u8a[t] = (unsigned)f2bf(pv[2 * t]) | ((unsigned)f2bf(pv[2 * t + 1]) << 16);
#pragma unroll
      for (int t = 0; t < 8; ++t)
        pu[t] = (unsigned)__shfl_xor((int)u8a[t], 32, 64);
#pragma unroll
      for (int s2 = 0; s2 < 2; ++s2) {
        u32x4 fu;
        if (hi == 0) {
          fu[0] = u8a[4 * s2]; fu[1] = u8a[4 * s2 + 1];
          fu[2] = pu[4 * s2];  fu[3] = pu[4 * s2 + 1];
        } else {
          fu[0] = pu[4 * s2 + 2];  fu[1] = pu[4 * s2 + 3];
          fu[2] = u8a[4 * s2 + 2]; fu[3] = u8a[4 * s2 + 3];
        }
        pfrag[nt][s2] = __builtin_bit_cast(short8, fu);
      }
    }

#pragma unroll
    for (int s2 = 0; s2 < 2; ++s2) {
#pragma unroll
      for (int dt = 0; dt < 2; ++dt) {
        const int rV = dt * 32 + l31;
        const int c = kh * 4 + s2 * 2 + hi;
        short8 bv = *(const short8*)&Vs[rV * 128 + ((c ^ (rV & 15)) * 8)];
        oacc[0][dt] = __builtin_amdgcn_mfma_f32_32x32x16_bf16(pfrag[0][s2], bv, oacc[0][dt], 0, 0, 0);
        oacc[1][dt] = __builtin_amdgcn_mfma_f32_32x32x16_bf16(pfrag[1][s2], bv, oacc[1][dt], 0, 0, 0);
      }
    }
  }

#pragma unroll
  for (int nt = 0; nt < 2; ++nt)
    den[nt] += __shfl_xor(den[nt], 32, 64);

  __syncthreads();
  if (kh == 0) {
#pragma unroll
    for (int nt = 0; nt < 2; ++nt) {
#pragma unroll
      for (int dt = 0; dt < 2; ++dt)
#pragma unroll
        for (int r = 0; r < 16; ++r) {
          const int row = qh * 64 + nt * 32 + (r & 3) + 8 * (r >> 2) + 4 * hi;
          Of[row][dt * 32 + l31] = oacc[nt][dt][r];
        }
      if (hi == 0) Dd[qh * 64 + nt * 32 + l31] = den[nt];
    }
  }
  __syncthreads();
  if (kh == 1) {
#pragma unroll
    for (int nt = 0; nt < 2; ++nt) {
#pragma unroll
      for (int dt = 0; dt < 2; ++dt)
#pragma unroll
        for (int r = 0; r < 16; ++r) {
          const int row = qh * 64 + nt * 32 + (r & 3) + 8 * (r >> 2) + 4 * hi;
          Of[row][dt * 32 + l31] += oacc[nt][dt][r];
        }
      if (hi == 0) Dd[qh * 64 + nt * 32 + l31] += den[nt];
    }
  }
  __syncthreads();

  {
    const int ql = tid >> 1, half = tid & 1;
    const int b = bh >> 4, h = bh & 15;
    const float invd = __builtin_amdgcn_rcpf(Dd[ql]);
    float* op = &out[(((size_t)b * N_ + q0 + ql) * H_ + h) * HD_ + half * 32];
#pragma unroll
    for (int j = 0; j < 8; ++j) {
      float4 o = *(const float4*)&Of[ql][half * 32 + j * 4];
      o.x *= invd; o.y *= invd; o.z *= invd; o.w *= invd;
      *(float4*)&op[j * 4] = o;
    }
  }
}

// ---------------------------------------------------------------------------
extern "C" void kernel_launch(void* const* d_in, const int* in_sizes, int n_in,
                              void* d_out, int out_size, void* d_ws, size_t ws_size,
                              hipStream_t stream) {
  const float* x    = (const float*)d_in[0];
  const float* Wqkv = (const float*)d_in[1];
  const float* bqkv = (const float*)d_in[2];
  const float* Wp1  = (const float*)d_in[3];
  const float* bp1  = (const float*)d_in[4];
  const float* Wp2  = (const float*)d_in[5];
  const float* bp2  = (const float*)d_in[6];
  const float* Wf   = (const float*)d_in[7];
  float* out = (float*)d_out;

  char* w = (char*)d_ws;
  float* qkv = (float*)w;               w += (size_t)ROWS * TDIM * 4;
  float* sumsq = (float*)w;             w += (size_t)ROWS * 4;
  ushort_t* Ms  = (ushort_t*)w;         w += 2 * 4096 * 2;
  ushort_t* W1s = (ushort_t*)w;         w += 2 * 8192 * 2;
  ushort_t* W2s = (ushort_t*)w;         w += 2 * 8192 * 2;
  unsigned short* Xs = (unsigned short*)w; w += (size_t)ROWS * 2048 * 2;
  unsigned short* Wt = (unsigned short*)w; w += (size_t)TDIM * 2048 * 2;
  unsigned short* Qc = (unsigned short*)w; w += (size_t)32 * N_ * 128 * 2;
  unsigned short* Kc = (unsigned short*)w; w += (size_t)32 * N_ * 128 * 2;
  unsigned short* Vt = (unsigned short*)w; w += (size_t)32 * 64 * N_ * 2;

  // fused prologue: blocks 0-2 = {compute_M, prep_w, zero_sumsq} (hide under
  // the split streams), 3-770 = split_W, 771-4866 = split_X.
  hipLaunchKernelGGL(prologue, dim3(4867), dim3(256), 0, stream,
                     x, Wqkv, Wf, Wp1, Wp2, Xs, Wt, Ms, W1s, W2s, sumsq);
  hipLaunchKernelGGL(gemm10, dim3(256), dim3(512), 0, stream, Xs, Wt, bqkv, qkv, sumsq);
  hipLaunchKernelGGL(prep_wave, dim3(2048), dim3(256), 0, stream,
                     qkv, sumsq, W1s, bp1, W2s, bp2, Ms, Qc, Kc, Vt);
  hipLaunchKernelGGL(attn3, dim3(N_ / 128, B_ * H_), dim3(256), 0, stream,
                     Qc, Kc, Vt, out);
}

// Round 13
// 335.654 us; speedup vs baseline: 1.0464x; 1.0464x over previous
//
#include <hip/hip_runtime.h>
#include <math.h>

#define B_    2
#define N_    2048
#define DIM_  1024
#define H_    16
#define HD_   64
#define TDIM  3072      // 3*DIM
#define ROWS  4096      // B*N
#define PI_F  3.14159265358979323846f
#define SCALE_F 0.125f

typedef short short8 __attribute__((ext_vector_type(8)));
typedef float f32x4 __attribute__((ext_vector_type(4)));
typedef float f32x16 __attribute__((ext_vector_type(16)));
typedef unsigned u32x4 __attribute__((ext_vector_type(4)));
typedef unsigned uint2v __attribute__((ext_vector_type(2)));
typedef unsigned short ushort_t;

// 2-op bf16 round (round-half-up)
__device__ __forceinline__ unsigned short f2bf(float x) {
  return (unsigned short)((__float_as_uint(x) + 0x8000u) >> 16);
}
__device__ __forceinline__ float bf2f(unsigned short h) {
  return __uint_as_float(((unsigned)h) << 16);
}
__device__ __forceinline__ float inv_norm(float s) {
  return __builtin_amdgcn_rsqf(fmaxf(s, 1e-24f));
}
// tanh via hw exp2 + rcp (no full-precision divide)
__device__ __forceinline__ float fast_tanh(float x) {
  const float e = __builtin_amdgcn_exp2f(2.885390081777927f * x);  // exp(2x)
  return 1.0f - 2.0f * __builtin_amdgcn_rcpf(e + 1.0f);
}

// DPP lane reductions (VALU, ~4-8cy/level vs ds_bpermute ~30cy)
template <int CTRL>
__device__ __forceinline__ float dpp_addf(float v) {
  int x = __builtin_amdgcn_update_dpp(0, __float_as_int(v), CTRL, 0xF, 0xF, true);
  return v + __int_as_float(x);
}
__device__ __forceinline__ float red16(float s) {   // sum over 16-lane rows
  s = dpp_addf<0xB1>(s);
  s = dpp_addf<0x4E>(s);
  s = dpp_addf<0x141>(s);
  s = dpp_addf<0x140>(s);
  return s;
}
__device__ __forceinline__ float red8(float s) {    // sum over 8-lane groups
  s = dpp_addf<0xB1>(s);
  s = dpp_addf<0x4E>(s);
  s = dpp_addf<0x141>(s);
  return s;
}
// lane i <-> lane i+32 exchange via permlane32_swap (VALU, replaces ds_bpermute)
__device__ __forceinline__ float xchg32(float x, bool hi32) {
  uint2v pr = __builtin_amdgcn_permlane32_swap(__float_as_uint(x),
                                               __float_as_uint(x), false, false);
  return __uint_as_float(hi32 ? pr[0] : pr[1]);
}

// async global->LDS, 16B per lane; LDS dest = wave-uniform base + lane*16
__device__ __forceinline__ void gl_lds16(const void* g, void* l) {
  __builtin_amdgcn_global_load_lds(
      (const __attribute__((address_space(1))) unsigned int*)g,
      (__attribute__((address_space(3))) unsigned int*)l, 16, 0, 0);
}

// ---------------------------------------------------------------------------
// prologue: ALL pre-GEMM prep fused into one launch. Single-block jobs
// (compute_M, prep_w, zero_sumsq) are blocks 0-2 (dispatched first) and hide
// under the 4096-block split_X stream + 768-block split_W.
// ---------------------------------------------------------------------------
__global__ __launch_bounds__(256) void prologue(
    const float* __restrict__ X, const float* __restrict__ Wqkv,
    const float* __restrict__ Wf, const float* __restrict__ Wp1,
    const float* __restrict__ Wp2,
    unsigned short* __restrict__ Xs, unsigned short* __restrict__ Wt,
    ushort_t* __restrict__ Ms, ushort_t* __restrict__ W1s,
    ushort_t* __restrict__ W2s, float* __restrict__ sumsq) {
  __shared__ __align__(16) char pls[32768];
  const int bid = blockIdx.x;
  const int tid = threadIdx.x;

  if (bid == 0) {
    // ---- compute_M: M = (I + 0.1*Wf)^10 via A^2,A^4,A^8,A^10 (4 matmuls).
    float* P = (float*)pls;
    float* Q = (float*)(pls + 16384);
    for (int i = tid; i < 4096; i += 256)
      P[i] = 0.1f * Wf[i] + (((i >> 6) == (i & 63)) ? 1.0f : 0.0f);
    __syncthreads();
    float acc[16];
#define MM64(Xb, Yb) \
    _Pragma("unroll") \
    for (int jo = 0; jo < 16; ++jo) { \
      const int i_ = tid + jo * 256; \
      const int r_ = i_ >> 6, c_ = i_ & 63; \
      float s0 = 0.f, s1 = 0.f, s2 = 0.f, s3 = 0.f; \
      _Pragma("unroll") \
      for (int e = 0; e < 64; e += 4) { \
        s0 = fmaf(Xb[r_ * 64 + e],     Yb[e * 64 + c_], s0); \
        s1 = fmaf(Xb[r_ * 64 + e + 1], Yb[(e + 1) * 64 + c_], s1); \
        s2 = fmaf(Xb[r_ * 64 + e + 2], Yb[(e + 2) * 64 + c_], s2); \
        s3 = fmaf(Xb[r_ * 64 + e + 3], Yb[(e + 3) * 64 + c_], s3); \
      } \
      acc[jo] = (s0 + s1) + (s2 + s3); \
    }
    MM64(P, P)
#pragma unroll
    for (int jo = 0; jo < 16; ++jo) Q[tid + jo * 256] = acc[jo];
    __syncthreads();
    MM64(Q, Q)
#pragma unroll
    for (int jo = 0; jo < 16; ++jo) P[tid + jo * 256] = acc[jo];
    __syncthreads();
    MM64(P, P)
    __syncthreads();
#pragma unroll
    for (int jo = 0; jo < 16; ++jo) P[tid + jo * 256] = acc[jo];
    __syncthreads();
    MM64(P, Q)
#pragma unroll
    for (int jo = 0; jo < 16; ++jo) {
      const int i_ = tid + jo * 256;
      const int r_ = i_ >> 6, c_ = i_ & 63;
      const ushort_t hi = f2bf(acc[jo]);
      Ms[c_ * 64 + r_] = hi;
      Ms[4096 + c_ * 64 + r_] = f2bf(acc[jo] - bf2f(hi));
    }
#undef MM64
  } else if (bid == 1) {
    // ---- prep_w
    for (int i = tid; i < 8192; i += 256) {
      const int n = i >> 6, k = i & 63;
      const float v = Wp1[k * 128 + n];
      const ushort_t hi = f2bf(v);
      W1s[i] = hi; W1s[8192 + i] = f2bf(v - bf2f(hi));
    }
    for (int i = tid; i < 8192; i += 256) {
      const int n = i >> 7, k = i & 127;
      const float v = Wp2[k * 64 + n];
      const ushort_t hi = f2bf(v);
      W2s[i] = hi; W2s[8192 + i] = f2bf(v - bf2f(hi));
    }
  } else if (bid == 2) {
    // ---- zero_sumsq
#pragma unroll
    for (int j = 0; j < 16; ++j) sumsq[j * 256 + tid] = 0.0f;
  } else if (bid < 771) {
    // ---- split_W: 768 blocks
    const int wb = bid - 3;
    const int n0 = (wb % 48) * 64, k0 = (wb / 48) * 64;
    float (*T)[68] = (float(*)[68])pls;
    for (int l = tid; l < 1024; l += 256) {
      const int r = l >> 4, c = (l & 15) * 4;
      *(float4*)&T[r][c] = *(const float4*)&Wqkv[(size_t)(k0 + r) * TDIM + n0 + c];
    }
    __syncthreads();
    const int n = tid >> 2, q = (tid & 3) * 16;
    alignas(16) unsigned short hi16[16];
    alignas(16) unsigned short lo16[16];
#pragma unroll
    for (int j = 0; j < 16; ++j) {
      const float v = T[q + j][n];
      const unsigned short h = f2bf(v);
      hi16[j] = h; lo16[j] = f2bf(v - bf2f(h));
    }
    unsigned short* dst = &Wt[(size_t)(n0 + n) * 2048];
    *(uint4*)&dst[k0 + q]            = *(uint4*)&hi16[0];
    *(uint4*)&dst[k0 + q + 8]        = *(uint4*)&hi16[8];
    *(uint4*)&dst[1024 + k0 + q]     = *(uint4*)&lo16[0];
    *(uint4*)&dst[1024 + k0 + q + 8] = *(uint4*)&lo16[8];
  } else {
    // ---- split_X: 4096 blocks
    const int gid = (bid - 771) * 256 + tid;
    const int m = gid >> 8, c = (gid & 255) * 4;
    float4 v = *(const float4*)&X[(size_t)m * 1024 + c];
    ushort4 hi, lo;
    hi.x = f2bf(v.x); lo.x = f2bf(v.x - bf2f(hi.x));
    hi.y = f2bf(v.y); lo.y = f2bf(v.y - bf2f(hi.y));
    hi.z = f2bf(v.z); lo.z = f2bf(v.z - bf2f(hi.z));
    hi.w = f2bf(v.w); lo.w = f2bf(v.w - bf2f(hi.w));
    *(ushort4*)&Xs[(size_t)m * 2048 + c] = hi;
    *(ushort4*)&Xs[(size_t)m * 2048 + 1024 + c] = lo;
  }
}

// ---------------------------------------------------------------------------
// gemm10: 256x192 tile, grid 256 blocks = 1/CU, 8 waves as 4M x 2N.
// Barrier-minimized schedule (R11, verified): 5 barriers/k, counted vmcnt.
// ---------------------------------------------------------------------------
#define BAR   __builtin_amdgcn_s_barrier()
#define LGKM  asm volatile("s_waitcnt lgkmcnt(0)")
#define SB    __builtin_amdgcn_sched_barrier(0)
#define PRIO1 __builtin_amdgcn_s_setprio(1)
#define PRIO0 __builtin_amdgcn_s_setprio(0)
#define WAITV(n) asm volatile("s_waitcnt vmcnt(" #n ")")

__global__ __launch_bounds__(512, 2) void gemm10(const unsigned short* __restrict__ Xs,
                                                 const unsigned short* __restrict__ Wt,
                                                 const float* __restrict__ bias,
                                                 float* __restrict__ C,
                                                 float* __restrict__ sumsq) {
  __shared__ __align__(16) ushort_t Ab[2][256 * 64];   // 2 x 32 KiB
  __shared__ __align__(16) ushort_t Bb0[192 * 64];     // 24 KiB (hi)
  __shared__ __align__(16) ushort_t Bb1[192 * 64];     // 24 KiB (lo)
  const int tid = threadIdx.x;
  const int wv = tid >> 6, ln = tid & 63;
  const int l16 = ln & 15, quad = ln >> 4;
  const int wm = wv >> 1, wn = wv & 1;         // 4M x 2N waves
  // XCD-aware bijective swizzle (256 % 8 == 0)
  const int flat = blockIdx.x;
  const int swz = (flat & 7) * 32 + (flat >> 3);
  const int row0 = (swz >> 4) * 256, col0 = (swz & 15) * 192;
  const int lr = ln >> 3, sg8 = (ln & 7) ^ lr;   // staging sub-row + swizzled slot

  f32x4 acc[4][6];
#pragma unroll
  for (int i = 0; i < 4; ++i)
#pragma unroll
    for (int j = 0; j < 6; ++j) acc[i][j] = {0.f, 0.f, 0.f, 0.f};

#define STAGE_A(dstBuf, koff) do { \
    _Pragma("unroll") for (int j_ = 0; j_ < 4; ++j_) { \
      const int g_ = wv + j_ * 8; \
      gl_lds16(&Xs[(size_t)(row0 + g_ * 8 + lr) * 2048 + (koff) + sg8 * 8], \
               (char*)(dstBuf) + g_ * 1024); \
    } \
  } while (0)
#define STAGE_B(dstBuf, koff) do { \
    _Pragma("unroll") for (int j_ = 0; j_ < 3; ++j_) { \
      const int g_ = wv + j_ * 8; \
      gl_lds16(&Wt[(size_t)(col0 + g_ * 8 + lr) * 2048 + (koff) + sg8 * 8], \
               (char*)(dstBuf) + g_ * 1024); \
    } \
  } while (0)

#define LDA(Abuf, mh) do { \
    _Pragma("unroll") for (int j_ = 0; j_ < 2; ++j_) { \
      const int rr_ = wm * 64 + (mh) * 32 + j_ * 16 + l16; \
      _Pragma("unroll") for (int kk_ = 0; kk_ < 2; ++kk_) \
        afr[j_][kk_] = *(const short8*)&(Abuf)[rr_ * 64 + (((kk_ * 4 + quad) ^ (l16 & 7)) * 8)]; \
    } \
  } while (0)

#define LDB(Bbuf, nh) do { \
    _Pragma("unroll") for (int j_ = 0; j_ < 3; ++j_) { \
      const int rr_ = wn * 96 + (nh) * 48 + j_ * 16 + l16; \
      _Pragma("unroll") for (int kk_ = 0; kk_ < 2; ++kk_) \
        bfr[(nh) * 3 + j_][kk_] = *(const short8*)&(Bbuf)[rr_ * 64 + (((kk_ * 4 + quad) ^ (l16 & 7)) * 8)]; \
    } \
  } while (0)

#define MFMA_Q(mh, nh) do { \
    _Pragma("unroll") for (int j_ = 0; j_ < 2; ++j_) \
    _Pragma("unroll") for (int i_ = 0; i_ < 3; ++i_) \
    _Pragma("unroll") for (int kk_ = 0; kk_ < 2; ++kk_) \
      acc[(mh) * 2 + j_][(nh) * 3 + i_] = __builtin_amdgcn_mfma_f32_16x16x32_bf16( \
          afr[j_][kk_], bfr[(nh) * 3 + i_][kk_], acc[(mh) * 2 + j_][(nh) * 3 + i_], 0, 0, 0); \
  } while (0)

  // prologue: issue order Bhi0, Ahi0, Alo0, Blo0; keep newest 7 in flight
  STAGE_B(Bb0, 0);
  STAGE_A(Ab[0], 0);
  STAGE_A(Ab[1], 1024);
  STAGE_B(Bb1, 1024);
  WAITV(7);
  BAR;

  short8 afr[2][2], bfr[6][2];
#pragma unroll 2
  for (int k = 0; k < 16; ++k) {
    ushort_t* Ahi = Ab[k & 1];
    ushort_t* Alo = Ab[(k & 1) ^ 1];
    const int kn = (k + 1) * 64;
    const bool more = (k < 15);

    // ======== tile 0: Ahi x Bhi (no staging, no intra-tile barriers) ====
    LDA(Ahi, 0); LDB(Bb0, 0);
    PRIO1; MFMA_Q(0, 0); PRIO0;
    LDB(Bb0, 1);
    PRIO1; MFMA_Q(0, 1); PRIO0;
    LDA(Ahi, 1);
    PRIO1; MFMA_Q(1, 0); PRIO0;
    PRIO1; MFMA_Q(1, 1); PRIO0;
    WAITV(3); SB; BAR;             // Alo_k landed & visible (keep Blo_k)

    // ======== tile 1: Alo x Bhi ========
    LDA(Alo, 0); LDB(Bb0, 0);
    PRIO1; MFMA_Q(0, 0); PRIO0;
    LDB(Bb0, 1);
    PRIO1; MFMA_Q(0, 1); PRIO0;
    LGKM; SB; BAR;                 // all waves' Bb0 reads complete
    if (more) STAGE_B(Bb0, kn);    // Bhi_{k+1}
    LDA(Alo, 1);
    PRIO1; MFMA_Q(1, 0); PRIO0;
    PRIO1; MFMA_Q(1, 1); PRIO0;
    LGKM;                          // all own Alo reads complete
    if (more) { WAITV(3); }        // drain Blo_k (t2 reads it), keep Bhi'
    else      { WAITV(0); }
    SB; BAR;
    if (more) STAGE_A(Alo, kn);    // Ahi_{k+1} -> A[(k+1)&1]

    // ======== tile 2: Ahi x Blo ========
    LDA(Ahi, 0); LDB(Bb1, 0);
    PRIO1; MFMA_Q(0, 0); PRIO0;
    LDB(Bb1, 1);
    PRIO1; MFMA_Q(0, 1); PRIO0;
    LDA(Ahi, 1);
    PRIO1; MFMA_Q(1, 0); PRIO0;
    PRIO1; MFMA_Q(1, 1); PRIO0;
    LGKM; SB; BAR;                 // all waves' Ahi/Bb1 reads complete
    if (more) { STAGE_A(Ahi, 1024 + kn); STAGE_B(Bb1, 1024 + kn); } // Alo',Blo'
    if (more) { WAITV(7); }        // drain Bhi'+Ahi', keep Alo'+Blo'
    else      { WAITV(0); }
    SB; BAR;                       // next-k inputs visible
  }
#undef STAGE_A
#undef STAGE_B
#undef LDA
#undef LDB
#undef MFMA_Q

  // ---- epilogue: bias + store + per-row sumsq (DPP 16-lane reduce)
  float ps[4][4];
#pragma unroll
  for (int mi = 0; mi < 4; ++mi)
#pragma unroll
    for (int r = 0; r < 4; ++r) ps[mi][r] = 0.f;
#pragma unroll
  for (int ni = 0; ni < 6; ++ni) {
    const int col = col0 + wn * 96 + ni * 16 + l16;
    const float bb = bias[col];
#pragma unroll
    for (int mi = 0; mi < 4; ++mi) {
#pragma unroll
      for (int r = 0; r < 4; ++r) {
        const int row = row0 + wm * 64 + mi * 16 + quad * 4 + r;
        const float o = acc[mi][ni][r] + bb;
        C[(size_t)row * TDIM + col] = o;
        ps[mi][r] = fmaf(o, o, ps[mi][r]);
      }
    }
  }
#pragma unroll
  for (int mi = 0; mi < 4; ++mi) {
#pragma unroll
    for (int r = 0; r < 4; ++r) {
      const float v = red16(ps[mi][r]);
      if (l16 == 0)
        atomicAdd(&sumsq[row0 + wm * 64 + mi * 16 + quad * 4 + r], v);
    }
  }
}

// ---------------------------------------------------------------------------
// prep_wave: barrier-free per-wave prep. (256,2): the transport loop exposes
// 4 INDEPENDENT ~30-reg chains (unrolled r=0..3); at 56 VGPR only ~1.5 are
// live (VALUBusy 27%). Min-waves=2 caps at 256 VGPR -> allocator free to
// keep all 4 chains interleaved. Occupancy curve is settled: (256,4)/56/38%
// = 92us, (256,6)/36/59% = 104, (256,8)/32/79% = 95 -> registers, not
// occupancy, are the lever here.
// ---------------------------------------------------------------------------
__global__ __launch_bounds__(256, 2) void prep_wave(
    const float* __restrict__ qkv, const float* __restrict__ sumsq,
    const ushort_t* __restrict__ W1s, const float* __restrict__ bp1,
    const ushort_t* __restrict__ W2s, const float* __restrict__ bp2,
    const ushort_t* __restrict__ Ms,
    ushort_t* __restrict__ Qc, ushort_t* __restrict__ Kc,
    ushort_t* __restrict__ Vt) {
  __shared__ __align__(16) char smem[4 * 4608];
  const int tid = threadIdx.x;
  const int wv = tid >> 6, ln = tid & 63;
  const int l16 = ln & 15, quad = ln >> 4;
  const bool hi32 = (ln >= 32);
  char* wscr = smem + wv * 4608;
  ushort_t (*T)[72]   = (ushort_t(*)[72])(wscr);           // 2304 B
  ushort_t (*Z0)[72]  = (ushort_t(*)[72])(wscr);           // alias T (post-amp)
  ushort_t (*Hs)[72]  = (ushort_t(*)[72])(wscr + 2304);    // 2304 B (half-H)
  ushort_t (*Vs)[72]  = (ushort_t(*)[72])(wscr + 2304);    // alias Hs (pre-L1)
  ushort_t (*Z1)[72]  = (ushort_t(*)[72])(wscr + 2304);    // alias Hs (post-aH)

  const int gw = blockIdx.x * 4 + wv;
  const int p0 = gw * 8;
  const int bh = p0 >> 11, n0 = p0 & 2047;
  const int b = bh >> 4, h = bh & 15;

  // ---- stage A: T A-frags (regs) + T scratch + row norms + V out
  short8 aTh[2], aTl[2];
  float invt_l;   // inv row norm for MLP row l16 (held by all quads)
  {
    const int tp = l16 & 7, tisk = l16 >> 3;
    const size_t tb = ((size_t)(b * N_ + n0 + tp)) * TDIM + h * HD_ +
                      tisk * 1024 + quad * 8;
    const float inv = inv_norm(sumsq[b * N_ + n0 + tp]);
    float tvv[16];
    float4 t0 = *(const float4*)&qkv[tb];
    float4 t1 = *(const float4*)&qkv[tb + 4];
    float4 t2 = *(const float4*)&qkv[tb + 32];
    float4 t3 = *(const float4*)&qkv[tb + 36];
    tvv[0]=t0.x*inv; tvv[1]=t0.y*inv; tvv[2]=t0.z*inv; tvv[3]=t0.w*inv;
    tvv[4]=t1.x*inv; tvv[5]=t1.y*inv; tvv[6]=t1.z*inv; tvv[7]=t1.w*inv;
    tvv[8]=t2.x*inv; tvv[9]=t2.y*inv; tvv[10]=t2.z*inv; tvv[11]=t2.w*inv;
    tvv[12]=t3.x*inv; tvv[13]=t3.y*inv; tvv[14]=t3.z*inv; tvv[15]=t3.w*inv;
    float s = 0.f;
#pragma unroll
    for (int j = 0; j < 16; ++j) s = fmaf(tvv[j], tvv[j], s);
    s += __shfl_xor(s, 16, 64);
    s += xchg32(s, hi32);
    invt_l = inv_norm(s);
    alignas(16) ushort_t hh[16];
    alignas(16) ushort_t llo[16];
#pragma unroll
    for (int j = 0; j < 16; ++j) {
      hh[j] = f2bf(tvv[j]);
      llo[j] = f2bf(tvv[j] - bf2f(hh[j]));
    }
    aTh[0] = *(const short8*)&hh[0]; aTh[1] = *(const short8*)&hh[8];
    aTl[0] = *(const short8*)&llo[0]; aTl[1] = *(const short8*)&llo[8];
    *(uint4*)&T[l16][quad * 8]      = *(const uint4*)&hh[0];
    *(uint4*)&T[l16][32 + quad * 8] = *(const uint4*)&hh[8];
  }
  // ---- V: |t|/||t||, transpose via scratch, one 16B store per lane
  {
    const int vp = ln >> 3, vc = (ln & 7) * 8;
    const size_t vb = ((size_t)(b * N_ + n0 + vp)) * TDIM + h * HD_ + 2048 + vc;
    float vv[8];
    float4 v0 = *(const float4*)&qkv[vb];
    float4 v1 = *(const float4*)&qkv[vb + 4];
    vv[0]=v0.x; vv[1]=v0.y; vv[2]=v0.z; vv[3]=v0.w;
    vv[4]=v1.x; vv[5]=v1.y; vv[6]=v1.z; vv[7]=v1.w;
    float sv = 0.f;
#pragma unroll
    for (int j = 0; j < 8; ++j) sv = fmaf(vv[j], vv[j], sv);
    sv = red8(sv);
    const float vinv = inv_norm(sv);
    alignas(16) ushort_t vb16[8];
#pragma unroll
    for (int j = 0; j < 8; ++j) vb16[j] = f2bf(fabsf(vv[j]) * vinv);
    *(uint4*)&Vs[vp][vc] = *(const uint4*)&vb16[0];
    alignas(16) ushort_t ov[8];
#pragma unroll
    for (int p = 0; p < 8; ++p) ov[p] = Vs[p][ln];
    *(uint4*)&Vt[((size_t)(bh * 64) + ln) * N_ + n0] = *(const uint4*)&ov[0];
  }
  // invt by output row (quad*4+r)
  float invt_r[4];
#pragma unroll
  for (int r = 0; r < 4; ++r) invt_r[r] = __shfl(invt_l, quad * 4 + r, 64);

  // ---- L1: H = tanh(T @ Wp1 + b1) [16 x 128], in two column-halves through
  //      the half-size Hs buffer (aH regs read between halves).  (48 MFMA)
  short8 aH[4];
#pragma unroll
  for (int half = 0; half < 2; ++half) {
#pragma unroll
    for (int ct = 0; ct < 4; ++ct) {
      const int colg = half * 64 + ct * 16 + l16;
      f32x4 c = {0.f, 0.f, 0.f, 0.f};
#pragma unroll
      for (int s = 0; s < 2; ++s) {
        short8 wh = *(const short8*)&W1s[(size_t)colg * 64 + s * 32 + quad * 8];
        short8 wl = *(const short8*)&W1s[8192 + (size_t)colg * 64 + s * 32 + quad * 8];
        c = __builtin_amdgcn_mfma_f32_16x16x32_bf16(aTh[s], wh, c, 0, 0, 0);
        c = __builtin_amdgcn_mfma_f32_16x16x32_bf16(aTh[s], wl, c, 0, 0, 0);
        c = __builtin_amdgcn_mfma_f32_16x16x32_bf16(aTl[s], wh, c, 0, 0, 0);
      }
      const float bb = bp1[colg];
#pragma unroll
      for (int r = 0; r < 4; ++r)
        Hs[quad * 4 + r][ct * 16 + l16] = f2bf(fast_tanh(c[r] + bb));
    }
    aH[half * 2]     = *(const short8*)&Hs[l16][quad * 8];
    aH[half * 2 + 1] = *(const short8*)&Hs[l16][32 + quad * 8];
  }

  // ---- L2 + z: rev = tanh(H@Wp2 + b2)*0.5 (revolutions: pi folds away);
  //      z = amp * e^{i*2*pi*rev} via hw v_sin/v_cos  (32 MFMA)
  {
#pragma unroll
    for (int ct = 0; ct < 4; ++ct) {
      const int d = ct * 16 + l16;
      f32x4 c = {0.f, 0.f, 0.f, 0.f};
#pragma unroll
      for (int s = 0; s < 4; ++s) {
        short8 wh = *(const short8*)&W2s[(size_t)d * 128 + s * 32 + quad * 8];
        short8 wl = *(const short8*)&W2s[8192 + (size_t)d * 128 + s * 32 + quad * 8];
        c = __builtin_amdgcn_mfma_f32_16x16x32_bf16(aH[s], wh, c, 0, 0, 0);
        c = __builtin_amdgcn_mfma_f32_16x16x32_bf16(aH[s], wl, c, 0, 0, 0);
      }
      const float b2v = bp2[d];
#pragma unroll
      for (int r = 0; r < 4; ++r) {
        const int row = quad * 4 + r;
        const float rev = fast_tanh(c[r] + b2v) * 0.5f;   // in [-0.5, 0.5]
        const float amp = bf2f(T[row][d]) * invt_r[r];
        const float sp = __builtin_amdgcn_sinf(rev);
        const float cp = __builtin_amdgcn_cosf(rev);
        Z0[row][d] = f2bf(amp * cp);   // overwrites T cell just read (in-order)
        Z1[row][d] = f2bf(amp * sp);   // overwrites dead Hs region
      }
    }
  }

  // ---- flow: F = Z @ M, kept in C-layout registers  (32 MFMA)
  f32x4 cc[2][4];
  {
    short8 aZ[2][2];
#pragma unroll
    for (int s = 0; s < 2; ++s) {
      aZ[0][s] = *(const short8*)&Z0[l16][s * 32 + quad * 8];
      aZ[1][s] = *(const short8*)&Z1[l16][s * 32 + quad * 8];
    }
#pragma unroll
    for (int ct = 0; ct < 4; ++ct) {
      const int colg = ct * 16 + l16;
      short8 mh[2], ml[2];
#pragma unroll
      for (int s = 0; s < 2; ++s) {
        mh[s] = *(const short8*)&Ms[(size_t)colg * 64 + s * 32 + quad * 8];
        ml[s] = *(const short8*)&Ms[4096 + (size_t)colg * 64 + s * 32 + quad * 8];
      }
#pragma unroll
      for (int comp = 0; comp < 2; ++comp) {
        f32x4 c = {0.f, 0.f, 0.f, 0.f};
#pragma unroll
        for (int s = 0; s < 2; ++s) {
          c = __builtin_amdgcn_mfma_f32_16x16x32_bf16(aZ[comp][s], mh[s], c, 0, 0, 0);
          c = __builtin_amdgcn_mfma_f32_16x16x32_bf16(aZ[comp][s], ml[s], c, 0, 0, 0);
        }
        cc[comp][ct] = c;
      }
    }
  }

  // ---- normalize + transport, natively in C-layout.
  const bool isk = quad >= 2;
#pragma unroll
  for (int r = 0; r < 4; ++r) {
    float fr[4], fi[4];
#pragma unroll
    for (int ct = 0; ct < 4; ++ct) { fr[ct] = cc[0][ct][r]; fi[ct] = cc[1][ct][r]; }
    float s = 0.f;
#pragma unroll
    for (int ct = 0; ct < 4; ++ct) s += fmaf(fr[ct], fr[ct], fi[ct] * fi[ct]);
    s = red16(s);
    const float invn_ = inv_norm(s);
#pragma unroll
    for (int ct = 0; ct < 4; ++ct) { fr[ct] *= invn_; fi[ct] *= invn_; }
    float or_[4], oi_[4];
#pragma unroll
    for (int ct = 0; ct < 4; ++ct) {
      or_[ct] = xchg32(fr[ct], hi32);
      oi_[ct] = xchg32(fi[ct], hi32);
    }
    float qr[4], qi[4], kr[4], ki[4];
#pragma unroll
    for (int ct = 0; ct < 4; ++ct) {
      qr[ct] = isk ? or_[ct] : fr[ct];
      qi[ct] = isk ? oi_[ct] : fi[ct];
      kr[ct] = isk ? fr[ct] : or_[ct];
      ki[ct] = isk ? fi[ct] : oi_[ct];
    }
    float sA = 0.f, sB = 0.f;
    float dr[4], di[4];
#pragma unroll
    for (int ct = 0; ct < 4; ++ct) {
      dr[ct] = kr[ct] - qr[ct];
      di[ct] = ki[ct] - qi[ct];
      sA += fmaf(dr[ct], dr[ct], -di[ct] * di[ct]);
      sB += 2.0f * dr[ct] * di[ct];
    }
    sA = red16(sA);
    sB = red16(sB);
    const float rad = __builtin_amdgcn_sqrtf(fmaf(sA, sA, sB * sB));
    const float ur = __builtin_amdgcn_sqrtf(fmaxf((rad + sA) * 0.5f, 0.0f));
    const float ui = copysignf(__builtin_amdgcn_sqrtf(fmaxf((rad - sA) * 0.5f, 0.0f)), sB);
    // exp(10*ur) = 2^(10*log2e*ur); sincos(10*ui) via hw (revolutions)
    const float er = __builtin_amdgcn_exp2f(14.426950408889634f * ur);
    const float rv = 1.5915494309189535f * ui;   // 10*ui / (2*pi)
    const float s10 = __builtin_amdgcn_sinf(rv);
    const float c10 = __builtin_amdgcn_cosf(rv);
    const float exr = er * c10, exi = er * s10;
    const float dnr = 1.0f + exr, dni = exi;
    const float rd2 = __builtin_amdgcn_rcpf(fmaf(dnr, dnr, dni * dni));
    const float tfr = dnr * rd2, tfi = -dni * rd2;
    const float omr = 1.0f - tfr, omi = -tfi;
    float ktr[4], kti[4];
    float s2 = 0.f;
#pragma unroll
    for (int ct = 0; ct < 4; ++ct) {
      ktr[ct] = kr[ct] * tfr - ki[ct] * tfi + qr[ct] * omr - qi[ct] * omi;
      kti[ct] = kr[ct] * tfi + ki[ct] * tfr + qr[ct] * omi + qi[ct] * omr;
      s2 += fmaf(ktr[ct], ktr[ct], kti[ct] * kti[ct]);
    }
    s2 = red16(s2);
    const float inv2 = inv_norm(s2);
    const int p = (quad & 1) * 4 + r;
    const size_t o = ((size_t)bh * N_ + n0 + p) * 128;
    if (!isk) {
#pragma unroll
      for (int ct = 0; ct < 4; ++ct) {
        const int d = ct * 16 + l16;
        Qc[o + d]      = f2bf(qr[ct]);
        Qc[o + 64 + d] = f2bf(qi[ct]);
      }
    } else {
#pragma unroll
      for (int ct = 0; ct < 4; ++ct) {
        const int d = ct * 16 + l16;
        Kc[o + d]      = f2bf(ktr[ct] * inv2);
        Kc[o + 64 + d] = f2bf(-kti[ct] * inv2);   // negated: S = qr.kr + qi.(-ki)
      }
    }
  }
}

// ---------------------------------------------------------------------------
// attn3: 32x32x16 MFMA flash. K prefetch via gl_lds16 double-buffer (R10),
// V prefetched 1 tile ahead into 2 uint4 regs (R12, no spill observed).
// ---------------------------------------------------------------------------
__global__ __launch_bounds__(256, 2) void attn3(
    const ushort_t* __restrict__ Qc, const ushort_t* __restrict__ Kc,
    const ushort_t* __restrict__ Vt, float* __restrict__ out) {
  __shared__ __align__(16) char smem[49664];
  ushort_t* Vs = (ushort_t*)(smem + 32768);   // 16 KiB
  float (*Of)[68] = (float(*)[68])smem;       // 34816 B, aliases K bufs
  float* Dd = (float*)(smem + 49152);

  const int tid = threadIdx.x;
  const int wv = tid >> 6, ln = tid & 63;
  const int l31 = ln & 31, hi = ln >> 5;
  const int l16 = ln & 15, quad = ln >> 4;
  const int qh = wv & 1, kh = wv >> 1;
  const int bh = blockIdx.y;
  const int q0 = blockIdx.x * 128;
  const size_t hb = (size_t)bh * N_;

  // K stage via gl_lds16: linear LDS slot u = i*256 + wv*64 + ln maps to
  // row r = u>>4, slot = u&15; source col c = slot ^ (r&15)  (pre-swizzled).
#define STAGE_K(dst, kt) do { \
    const size_t kb_ = (hb + (size_t)(kt) * 64) * 128; \
    _Pragma("unroll") for (int i_ = 0; i_ < 4; ++i_) { \
      const int r_ = i_ * 16 + wv * 4 + quad; \
      const int c_ = l16 ^ (r_ & 15); \
      gl_lds16(&Kc[kb_ + (size_t)r_ * 128 + c_ * 8], \
               (char*)(dst) + (i_ * 256 + wv * 64) * 16); \
    } \
  } while (0)

  short8 qf[2][8];
#pragma unroll
  for (int nt = 0; nt < 2; ++nt) {
    const size_t qrow = (hb + q0 + qh * 64 + nt * 32 + l31) * 128;
#pragma unroll
    for (int s = 0; s < 8; ++s)
      qf[nt][s] = *(const short8*)&Qc[qrow + s * 16 + hi * 8];
  }

  f32x16 oacc[2][2];
#pragma unroll
  for (int i = 0; i < 2; ++i)
#pragma unroll
    for (int j = 0; j < 2; ++j)
#pragma unroll
      for (int r = 0; r < 16; ++r) oacc[i][j][r] = 0.f;
  float den[2] = {0.f, 0.f};

  // V staging lane->element maps (constant across iterations)
  const int vrA = (tid + 0)   >> 3, vcA = (tid + 0)   & 7;
  const int vrB = (tid + 256) >> 3, vcB = (tid + 256) & 7;

  STAGE_K((ushort_t*)smem, 0);   // K tile 0 in flight
  uint4 vreg0, vreg1;            // V tile 0 prefetch (2 regs only)
  vreg0 = *(const uint4*)&Vt[((size_t)bh * 64 + vrA) * N_ + vcA * 8];
  vreg1 = *(const uint4*)&Vt[((size_t)bh * 64 + vrB) * N_ + vcB * 8];

  const int rK = kh * 32 + l31;
  for (int kt = 0; kt < N_ / 64; ++kt) {
    ushort_t* Ks = (ushort_t*)(smem + (kt & 1) * 16384);
    ushort_t* Kn = (ushort_t*)(smem + ((kt & 1) ^ 1) * 16384);
    BAR;   // all waves done reading Vs + Kn(=prev Ks) from previous iter

    // ds_write of vregs: compiler waits on the V loads (youngest) -> drains
    // ALL older vmem incl. this tile's K loads.
    *(uint4*)&Vs[vrA * 128 + ((vcA ^ (vrA & 15)) * 8)] = vreg0;
    *(uint4*)&Vs[vrB * 128 + ((vcB ^ (vrB & 15)) * 8)] = vreg1;
    if (kt + 1 < N_ / 64) {
      STAGE_K(Kn, kt + 1);           // issue K(t+1) first...
      vreg0 = *(const uint4*)&Vt[((size_t)bh * 64 + vrA) * N_ + (kt + 1) * 64 + vcA * 8];
      vreg1 = *(const uint4*)&Vt[((size_t)bh * 64 + vrB) * N_ + (kt + 1) * 64 + vcB * 8];
    }                                // ...then V(t+1) (youngest)
    LGKM; SB;
    BAR;   // Vs visible; K(t+1)/V(t+1) stay in flight across this barrier

    f32x16 sacc[2];
#pragma unroll
    for (int nt = 0; nt < 2; ++nt)
#pragma unroll
      for (int r = 0; r < 16; ++r) sacc[nt][r] = 0.f;
#pragma unroll
    for (int s = 0; s < 8; ++s) {
      const int c = s * 2 + hi;
      short8 ak = *(const short8*)&Ks[rK * 128 + ((c ^ (rK & 15)) * 8)];
      sacc[0] = __builtin_amdgcn_mfma_f32_32x32x16_bf16(ak, qf[0][s], sacc[0], 0, 0, 0);
      sacc[1] = __builtin_amdgcn_mfma_f32_32x32x16_bf16(ak, qf[1][s], sacc[1], 0, 0, 0);
    }

    short8 pfrag[2][2];
#pragma unroll
    for (int nt = 0; nt < 2; ++nt) {
      float pv[16];
      float dl = 0.f;
#pragma unroll
      for (int r = 0; r < 16; ++r) {
        pv[r] = __expf(sacc[nt][r] * SCALE_F);
        dl += pv[r];
      }
      den[nt] += dl;
      unsigned u8a[8], pu[8];
#pragma unroll
      for (int t = 0; t < 8; ++t)
        u8a[t] = (unsigned)f2bf(pv[2 * t]) | ((unsigned)f2bf(pv[2 * t + 1]) << 16);
#pragma unroll
      for (int t = 0; t < 8; ++t)
        pu[t] = (unsigned)__shfl_xor((int)u8a[t], 32, 64);
#pragma unroll
      for (int s2 = 0; s2 < 2; ++s2) {
        u32x4 fu;
        if (hi == 0) {
          fu[0] = u8a[4 * s2]; fu[1] = u8a[4 * s2 + 1];
          fu[2] = pu[4 * s2];  fu[3] = pu[4 * s2 + 1];
        } else {
          fu[0] = pu[4 * s2 + 2];  fu[1] = pu[4 * s2 + 3];
          fu[2] = u8a[4 * s2 + 2]; fu[3] = u8a[4 * s2 + 3];
        }
        pfrag[nt][s2] = __builtin_bit_cast(short8, fu);
      }
    }

#pragma unroll
    for (int s2 = 0; s2 < 2; ++s2) {
#pragma unroll
      for (int dt = 0; dt < 2; ++dt) {
        const int rV = dt * 32 + l31;
        const int c = kh * 4 + s2 * 2 + hi;
        short8 bv = *(const short8*)&Vs[rV * 128 + ((c ^ (rV & 15)) * 8)];
        oacc[0][dt] = __builtin_amdgcn_mfma_f32_32x32x16_bf16(pfrag[0][s2], bv, oacc[0][dt], 0, 0, 0);
        oacc[1][dt] = __builtin_amdgcn_mfma_f32_32x32x16_bf16(pfrag[1][s2], bv, oacc[1][dt], 0, 0, 0);
      }
    }
  }

#pragma unroll
  for (int nt = 0; nt < 2; ++nt)
    den[nt] += __shfl_xor(den[nt], 32, 64);

  __syncthreads();
  if (kh == 0) {
#pragma unroll
    for (int nt = 0; nt < 2; ++nt) {
#pragma unroll
      for (int dt = 0; dt < 2; ++dt)
#pragma unroll
        for (int r = 0; r < 16; ++r) {
          const int row = qh * 64 + nt * 32 + (r & 3) + 8 * (r >> 2) + 4 * hi;
          Of[row][dt * 32 + l31] = oacc[nt][dt][r];
        }
      if (hi == 0) Dd[qh * 64 + nt * 32 + l31] = den[nt];
    }
  }
  __syncthreads();
  if (kh == 1) {
#pragma unroll
    for (int nt = 0; nt < 2; ++nt) {
#pragma unroll
      for (int dt = 0; dt < 2; ++dt)
#pragma unroll
        for (int r = 0; r < 16; ++r) {
          const int row = qh * 64 + nt * 32 + (r & 3) + 8 * (r >> 2) + 4 * hi;
          Of[row][dt * 32 + l31] += oacc[nt][dt][r];
        }
      if (hi == 0) Dd[qh * 64 + nt * 32 + l31] += den[nt];
    }
  }
  __syncthreads();

  {
    const int ql = tid >> 1, half = tid & 1;
    const int b = bh >> 4, h = bh & 15;
    const float invd = __builtin_amdgcn_rcpf(Dd[ql]);
    float* op = &out[(((size_t)b * N_ + q0 + ql) * H_ + h) * HD_ + half * 32];
#pragma unroll
    for (int j = 0; j < 8; ++j) {
      float4 o = *(const float4*)&Of[ql][half * 32 + j * 4];
      o.x *= invd; o.y *= invd; o.z *= invd; o.w *= invd;
      *(float4*)&op[j * 4] = o;
    }
  }
}

// ---------------------------------------------------------------------------
extern "C" void kernel_launch(void* const* d_in, const int* in_sizes, int n_in,
                              void* d_out, int out_size, void* d_ws, size_t ws_size,
                              hipStream_t stream) {
  const float* x    = (const float*)d_in[0];
  const float* Wqkv = (const float*)d_in[1];
  const float* bqkv = (const float*)d_in[2];
  const float* Wp1  = (const float*)d_in[3];
  const float* bp1  = (const float*)d_in[4];
  const float* Wp2  = (const float*)d_in[5];
  const float* bp2  = (const float*)d_in[6];
  const float* Wf   = (const float*)d_in[7];
  float* out = (float*)d_out;

  char* w = (char*)d_ws;
  float* qkv = (float*)w;               w += (size_t)ROWS * TDIM * 4;
  float* sumsq = (float*)w;             w += (size_t)ROWS * 4;
  ushort_t* Ms  = (ushort_t*)w;         w += 2 * 4096 * 2;
  ushort_t* W1s = (ushort_t*)w;         w += 2 * 8192 * 2;
  ushort_t* W2s = (ushort_t*)w;         w += 2 * 8192 * 2;
  unsigned short* Xs = (unsigned short*)w; w += (size_t)ROWS * 2048 * 2;
  unsigned short* Wt = (unsigned short*)w; w += (size_t)TDIM * 2048 * 2;
  unsigned short* Qc = (unsigned short*)w; w += (size_t)32 * N_ * 128 * 2;
  unsigned short* Kc = (unsigned short*)w; w += (size_t)32 * N_ * 128 * 2;
  unsigned short* Vt = (unsigned short*)w; w += (size_t)32 * 64 * N_ * 2;

  // fused prologue: blocks 0-2 = {compute_M, prep_w, zero_sumsq} (hide under
  // the split streams), 3-770 = split_W, 771-4866 = split_X.
  hipLaunchKernelGGL(prologue, dim3(4867), dim3(256), 0, stream,
                     x, Wqkv, Wf, Wp1, Wp2, Xs, Wt, Ms, W1s, W2s, sumsq);
  hipLaunchKernelGGL(gemm10, dim3(256), dim3(512), 0, stream, Xs, Wt, bqkv, qkv, sumsq);
  hipLaunchKernelGGL(prep_wave, dim3(2048), dim3(256), 0, stream,
                     qkv, sumsq, W1s, bp1, W2s, bp2, Ms, Qc, Kc, Vt);
  hipLaunchKernelGGL(attn3, dim3(N_ / 128, B_ * H_), dim3(256), 0, stream,
                     Qc, Kc, Vt, out);
}